// Round 10
// baseline (316.524 us; speedup 1.0000x reference)
//
#include <hip/hip_runtime.h>
#include <hip/hip_fp16.h>
#include <math.h>

#define Bn 128
#define Nn 1000
#define Tn 50
#define En 32000
#define Rn 4
#define FSn 43
#define NSELn 500
#define NFtot (Nn * FSn)   // 43000

// LDS float offsets inside k_temporal
#define OBS0 0          // obs tile: (c*64+r)*51 + t, 9792 floats
#define WS2O 9792       // w_s2: 2880 floats
#define WM1O 12672      // w_m1: 189 floats
#define WM2O 12861      // w_m2: 1800 floats -> total 14661 floats = 58644 B

// ---------------------------------------------------------------------------
// Kernel 1: fused temporal features. 512 thr = 8 waves, 64 nodes per block.
// R9's inner bodies, but the big conv weights are staged in LDS (uniform-addr
// ds_read broadcast, imm offsets) instead of per-use global loads — R9's 3.5x
// VALU overhead was weight-fetch addressing/latency.
// Role split rebalanced for mid's 1.8x work:
//   w0..w2: short conv 16 t each + long-max third
//   w3..w7: mid conv 6 t each
// LDS 58.6 KB -> 2 blocks/CU = 16 waves/CU (~= R9's effective 13).
// ---------------------------------------------------------------------------
__global__ __launch_bounds__(512) void k_temporal(
    const float* __restrict__ obs,
    const float* __restrict__ w_s1, const float* __restrict__ b_s1,
    const float* __restrict__ w_s2, const float* __restrict__ b_s2,
    const float* __restrict__ w_m1, const float* __restrict__ b_m1,
    const float* __restrict__ w_m2, const float* __restrict__ b_m2,
    float* __restrict__ x)
{
    __shared__ float lds[14661];

    const int b     = blockIdx.x;
    const int tile0 = blockIdx.y * 64;
    const int tid   = threadIdx.x;
    const int lane  = tid & 63;
    const int w     = __builtin_amdgcn_readfirstlane(tid >> 6);   // 0..7
    const int nrows = (Nn - tile0) < 64 ? (Nn - tile0) : 64;

    // stage obs tile
    for (int c = 0; c < 3; ++c) {
        const float* srcp = obs + ((size_t)(b * 3 + c) * Nn + tile0) * Tn;
        for (int idx = tid; idx < nrows * Tn; idx += 512) {
            const int r = idx / Tn;
            const int t = idx - r * Tn;
            lds[OBS0 + (c * 64 + r) * 51 + t] = srcp[idx];
        }
    }
    // stage big weights
    for (int idx = tid; idx < 2880; idx += 512) lds[WS2O + idx] = w_s2[idx];
    for (int idx = tid; idx < 189;  idx += 512) lds[WM1O + idx] = w_m1[idx];
    for (int idx = tid; idx < 1800; idx += 512) lds[WM2O + idx] = w_m2[idx];
    __syncthreads();

    float acc[20];
    float mx0 = -1e30f, mx1 = -1e30f, mx2 = -1e30f;

    if (w < 3) {
        // ---------------- short path: t in [w*16, w*16+16) ----------------
        #pragma unroll
        for (int o = 0; o < 20; ++o) acc[o] = (w == 0) ? b_s2[o] : 0.f;

        const float s10 = b_s1[0], s11 = b_s1[1], s12 = b_s1[2];
        const int t0 = w * 16;

        #pragma unroll 1
        for (int t = t0; t < t0 + 16; ++t) {
            float ov[9];
            #pragma unroll
            for (int c = 0; c < 3; ++c)
                #pragma unroll
                for (int d = 0; d < 3; ++d)
                    ov[c * 3 + d] = lds[OBS0 + (c * 64 + lane) * 51 + t + d];

            float v0 = s10, v1 = s11, v2 = s12;
            #pragma unroll
            for (int c = 0; c < 3; ++c) {
                v0 += ov[c * 3 + 0] * w_s1[(0 * 3 + c) * 3 + 0]
                    + ov[c * 3 + 1] * w_s1[(0 * 3 + c) * 3 + 1]
                    + ov[c * 3 + 2] * w_s1[(0 * 3 + c) * 3 + 2];
                v1 += ov[c * 3 + 0] * w_s1[(1 * 3 + c) * 3 + 0]
                    + ov[c * 3 + 1] * w_s1[(1 * 3 + c) * 3 + 1]
                    + ov[c * 3 + 2] * w_s1[(1 * 3 + c) * 3 + 2];
                v2 += ov[c * 3 + 0] * w_s1[(2 * 3 + c) * 3 + 0]
                    + ov[c * 3 + 1] * w_s1[(2 * 3 + c) * 3 + 1]
                    + ov[c * 3 + 2] * w_s1[(2 * 3 + c) * 3 + 2];
            }
            v0 = fmaxf(v0, 0.f); v1 = fmaxf(v1, 0.f); v2 = fmaxf(v2, 0.f);
            #pragma unroll
            for (int o = 0; o < 20; ++o) {
                acc[o] += v0 * lds[WS2O + (o * 3 + 0) * 48 + t]
                        + v1 * lds[WS2O + (o * 3 + 1) * 48 + t]
                        + v2 * lds[WS2O + (o * 3 + 2) * 48 + t];
            }
        }

        // ---------------- long path third ----------------
        const int rb0 = OBS0 + (0 * 64 + lane) * 51;
        const int rb1 = OBS0 + (1 * 64 + lane) * 51;
        const int rb2 = OBS0 + (2 * 64 + lane) * 51;
        const int l0 = (w == 0) ? 0 : (w == 1) ? 17 : 34;
        const int l1 = (w == 0) ? 17 : (w == 1) ? 34 : 50;
        #pragma unroll 1
        for (int t = l0; t < l1; ++t) {
            mx0 = fmaxf(mx0, lds[rb0 + t]);
            mx1 = fmaxf(mx1, lds[rb1 + t]);
            mx2 = fmaxf(mx2, lds[rb2 + t]);
        }
    } else {
        // ---------------- mid path: t in [(w-3)*6, (w-3)*6+6) ------------
        #pragma unroll
        for (int o = 0; o < 20; ++o) acc[o] = (w == 3) ? b_m2[o] : 0.f;

        const float m10 = b_m1[0], m11 = b_m1[1], m12 = b_m1[2];
        const int t0 = (w - 3) * 6;

        #pragma unroll 1
        for (int t = t0; t < t0 + 6; ++t) {
            float v0 = m10, v1 = m11, v2 = m12;
            #pragma unroll
            for (int c = 0; c < 3; ++c) {
                const int base = OBS0 + (c * 64 + lane) * 51 + t;
                #pragma unroll
                for (int d = 0; d < 21; ++d) {
                    const float ov = lds[base + d];
                    v0 += ov * lds[WM1O + (0 * 3 + c) * 21 + d];
                    v1 += ov * lds[WM1O + (1 * 3 + c) * 21 + d];
                    v2 += ov * lds[WM1O + (2 * 3 + c) * 21 + d];
                }
            }
            v0 = fmaxf(v0, 0.f); v1 = fmaxf(v1, 0.f); v2 = fmaxf(v2, 0.f);
            #pragma unroll
            for (int o = 0; o < 20; ++o) {
                acc[o] += v0 * lds[WM2O + (o * 3 + 0) * 30 + t]
                        + v1 * lds[WM2O + (o * 3 + 1) * 30 + t]
                        + v2 * lds[WM2O + (o * 3 + 2) * 30 + t];
            }
        }
    }

    // ---- exchange partials via the (now dead) obs tile ----
    // waves 1,2  -> [23][64] at (w-1)*1472        (20 short + 3 long rows)
    // waves 4..7 -> [20][64] at 2944 + (w-4)*1280
    __syncthreads();
    if (w == 1 || w == 2) {
        float* r = lds + (w - 1) * 1472 + lane;
        #pragma unroll
        for (int o = 0; o < 20; ++o) r[o * 64] = acc[o];
        r[20 * 64] = mx0;
        r[21 * 64] = mx1;
        r[22 * 64] = mx2;
    } else if (w >= 4) {
        float* r = lds + 2944 + (w - 4) * 1280 + lane;
        #pragma unroll
        for (int o = 0; o < 20; ++o) r[o * 64] = acc[o];
    }
    __syncthreads();

    if (lane < nrows) {
        float* xp = x + ((size_t)b * Nn + tile0 + lane) * FSn;
        if (w == 0) {
            #pragma unroll
            for (int o = 0; o < 20; ++o) {
                const int a = o * 64 + lane;
                xp[o] = fmaxf(acc[o] + lds[a] + lds[1472 + a], 0.f);
            }
            {
                const int a0 = 20 * 64 + lane, a1 = 21 * 64 + lane, a2 = 22 * 64 + lane;
                xp[40] = fmaxf(fmaxf(mx0, fmaxf(lds[a0], lds[1472 + a0])), 0.f);
                xp[41] = fmaxf(fmaxf(mx1, fmaxf(lds[a1], lds[1472 + a1])), 0.f);
                xp[42] = fmaxf(fmaxf(mx2, fmaxf(lds[a2], lds[1472 + a2])), 0.f);
            }
        } else if (w == 3) {
            #pragma unroll
            for (int o = 0; o < 20; ++o) {
                const int a = 2944 + o * 64 + lane;
                xp[20 + o] = fmaxf(acc[o] + lds[a] + lds[a + 1280]
                                          + lds[a + 2560] + lds[a + 3840], 0.f);
            }
        }
    }
}

// ---------------------------------------------------------------------------
// Transpose + fp16 convert: x[b][nf] (f32) -> xT[nf][b] (f16)
// ---------------------------------------------------------------------------
__global__ __launch_bounds__(256) void k_transpose(const float* __restrict__ x,
                                                   __half* __restrict__ xT)
{
    __shared__ float tile[64][129];
    const int c0  = blockIdx.x * 64;
    const int tid = threadIdx.x;

    const int j  = tid & 63;
    const int bs = tid >> 6;
    for (int bb = bs; bb < Bn; bb += 4) {
        int c = c0 + j;
        if (c < NFtot) tile[j][bb] = x[(size_t)bb * NFtot + c];
    }
    __syncthreads();

    const int b  = tid & 127;
    for (int jj = (tid >> 7); jj < 64; jj += 2) {
        int c = c0 + jj;
        if (c < NFtot) xT[(size_t)c * Bn + b] = __float2half(tile[jj][b]);
    }
}

// ---------------------------------------------------------------------------
// CSR build
// ---------------------------------------------------------------------------
__global__ void k_zero(int* __restrict__ cnt, int* __restrict__ pos)
{
    int i = blockIdx.x * blockDim.x + threadIdx.x;
    if (i < 4096) { cnt[i] = 0; pos[i] = 0; }
}

__global__ void k_count(const int* __restrict__ ei, const int* __restrict__ et,
                        int* __restrict__ cnt)
{
    int e = blockIdx.x * blockDim.x + threadIdx.x;
    if (e < En) {
        int dst = ei[En + e];
        atomicAdd(&cnt[dst * Rn + et[e]], 1);
    }
}

__global__ __launch_bounds__(1024) void k_scan(const int* __restrict__ cnt,
                                               int* __restrict__ off)
{
    __shared__ int sums[1024];
    int tid = threadIdx.x;
    int base = tid * 4;
    int c[4];
    int ts = 0;
    #pragma unroll
    for (int k = 0; k < 4; ++k) {
        int i = base + k;
        c[k] = (i < Nn * Rn) ? cnt[i] : 0;
        ts += c[k];
    }
    sums[tid] = ts;
    __syncthreads();
    for (int d = 1; d < 1024; d <<= 1) {
        int t = 0;
        if (tid >= d) t = sums[tid - d];
        __syncthreads();
        sums[tid] += t;
        __syncthreads();
    }
    int excl = sums[tid] - ts;
    #pragma unroll
    for (int k = 0; k < 4; ++k) {
        int i = base + k;
        off[i] = excl;
        excl += c[k];
    }
}

__global__ void k_fill(const int* __restrict__ ei, const int* __restrict__ et,
                       const int* __restrict__ off, int* __restrict__ pos,
                       int* __restrict__ csr)
{
    int e = blockIdx.x * blockDim.x + threadIdx.x;
    if (e < En) {
        int src = ei[e];
        int dst = ei[En + e];
        int seg = dst * Rn + et[e];
        int p = atomicAdd(&pos[seg], 1);
        csr[off[seg] + p] = src;
    }
}

// ---------------------------------------------------------------------------
// Kernel 2a: per-(selected dst, relation) mean aggregation, fp16 in/out.
// grid = 500*4; 256 thr = 8 f-chunks x 32 b-quads (4 halves = 8B per load).
// abar[i][r][f][b] (half) = mean over edges of xT[src][f][b].
// ---------------------------------------------------------------------------
__global__ __launch_bounds__(256) void k_agg4(
    const __half* __restrict__ xT,
    const int* __restrict__ csr, const int* __restrict__ off,
    const int* __restrict__ cnt, const int* __restrict__ sel,
    __half* __restrict__ abar)
{
    __shared__ int srcs[128];

    const int blk = blockIdx.x;
    const int i   = blk >> 2;
    const int r   = blk & 3;
    const int dst = sel[i];
    const int tid = threadIdx.x;
    const int b4  = tid & 31;      // 4-halves group over b
    const int fc  = tid >> 5;      // 0..7

    const int seg = dst * Rn + r;
    const int c   = cnt[seg];
    const int o   = off[seg];
    const int cc  = (c < 128) ? c : 128;
    if (tid < cc) srcs[tid] = csr[o + tid];
    __syncthreads();

    const int nk = (fc < 3) ? 6 : 5;   // f = fc + 8k < 43

    float4 acc[6];
    #pragma unroll
    for (int k = 0; k < 6; ++k) acc[k] = make_float4(0.f, 0.f, 0.f, 0.f);

    const float2* xT2 = (const float2*)xT;   // 1 float2 = 4 halves
    for (int j = 0; j < cc; ++j) {
        const int src = srcs[j];
        const float2* base = xT2 + (size_t)src * (FSn * 32) + (size_t)fc * 32 + b4;
        #pragma unroll
        for (int k = 0; k < 6; ++k) {
            if (k < nk) {
                float2 raw = base[k * 8 * 32];
                const __half2 h0 = ((const __half2*)&raw)[0];
                const __half2 h1 = ((const __half2*)&raw)[1];
                const float2 f0 = __half22float2(h0);
                const float2 f1 = __half22float2(h1);
                acc[k].x += f0.x; acc[k].y += f0.y;
                acc[k].z += f1.x; acc[k].w += f1.y;
            }
        }
    }

    const float inv = (c > 0) ? 1.f / (float)c : 0.f;
    float2* ab2 = (float2*)abar + (size_t)(i * Rn + r) * (FSn * 32) + (size_t)fc * 32 + b4;
    #pragma unroll
    for (int k = 0; k < 6; ++k) {
        if (k < nk) {
            float2 st;
            ((__half2*)&st)[0] = __floats2half2_rn(acc[k].x * inv, acc[k].y * inv);
            ((__half2*)&st)[1] = __floats2half2_rn(acc[k].z * inv, acc[k].w * inv);
            ab2[k * 8 * 32] = st;
        }
    }
}

// ---------------------------------------------------------------------------
// Kernel 2b: relational transform + root + leaky + final projection.
// grid = 500; 512 thr = 4 f-groups x 128 b. Reads abar(half) + xT(half).
// ---------------------------------------------------------------------------
__global__ __launch_bounds__(512) void k_trans(
    const __half* __restrict__ xT, const __half* __restrict__ abar,
    const float* __restrict__ w_rel, const float* __restrict__ w_root,
    const float* __restrict__ b_g,
    const float* __restrict__ w_fin, const float* __restrict__ b_fin,
    const float* __restrict__ la,
    const int* __restrict__ sel,
    float* __restrict__ logitT)
{
    __shared__ float red[FSn + 1][Bn];

    const int i   = blockIdx.x;
    const int dst = sel[i];
    const int tid = threadIdx.x;
    const int fs  = tid >> 7;
    const int b   = tid & 127;

    const int f0 = fs * 11;
    const int nf = (fs == 3) ? 10 : 11;

    float a[5][11];
    #pragma unroll
    for (int rr = 0; rr < 4; ++rr) {
        const __half* ap = abar + ((size_t)(i * Rn + rr) * FSn + f0) * Bn + b;
        #pragma unroll
        for (int k = 0; k < 11; ++k)
            a[rr][k] = (k < nf) ? __half2float(ap[(size_t)k * Bn]) : 0.f;
    }
    {
        const __half* xp = xT + ((size_t)dst * FSn + f0) * Bn + b;
        #pragma unroll
        for (int k = 0; k < 11; ++k)
            a[4][k] = (k < nf) ? __half2float(xp[(size_t)k * Bn]) : 0.f;
    }

    float accg[FSn];
    #pragma unroll
    for (int g = 0; g < FSn; ++g) accg[g] = 0.f;
    float psum = 0.f;

    #pragma unroll
    for (int k = 0; k < 11; ++k) {
        if (k < nf) {
            const int f = f0 + k;
            #pragma unroll
            for (int rr = 0; rr < 5; ++rr) {
                const float av = a[rr][k];
                const float* wrow = (rr < 4)
                    ? (w_rel + ((size_t)rr * FSn + f) * FSn)
                    : (w_root + (size_t)f * FSn);
                #pragma unroll
                for (int g = 0; g < FSn; ++g) accg[g] += av * wrow[g];
            }
            psum += a[4][k] * w_fin[1 + f];
        }
    }

    if (fs == 3) {
        #pragma unroll
        for (int g = 0; g < FSn; ++g) red[g][b] = accg[g];
        red[FSn][b] = psum;
    }
    __syncthreads();
    if (fs == 2) {
        #pragma unroll
        for (int g = 0; g < FSn; ++g) red[g][b] += accg[g];
        red[FSn][b] += psum;
    }
    __syncthreads();
    if (fs == 1) {
        #pragma unroll
        for (int g = 0; g < FSn; ++g) red[g][b] += accg[g];
        red[FSn][b] += psum;
    }
    __syncthreads();
    if (fs == 0) {
        float logit = b_fin[0] + w_fin[0] * la[(size_t)b * (NSELn + 1) + 1 + i]
                    + psum + red[FSn][b];
        #pragma unroll
        for (int g = 0; g < FSn; ++g) {
            float v = accg[g] + red[g][b] + b_g[g];
            v = (v > 0.f) ? v : 0.01f * v;
            logit += v * w_fin[44 + g];
        }
        logitT[(size_t)i * Bn + b] = logit;
    }
}

// ---------------------------------------------------------------------------
// Kernel 3: softmax over [0, logits(500)] per batch. Block per b.
// ---------------------------------------------------------------------------
__global__ __launch_bounds__(512) void k_softmax(const float* __restrict__ logitT,
                                                 float* __restrict__ out)
{
    __shared__ float red[512];
    const int b   = blockIdx.x;
    const int tid = threadIdx.x;

    const float l = (tid < NSELn) ? logitT[(size_t)tid * Bn + b] : -1e30f;
    red[tid] = l;
    __syncthreads();
    for (int s = 256; s > 0; s >>= 1) {
        if (tid < s) red[tid] = fmaxf(red[tid], red[tid + s]);
        __syncthreads();
    }
    const float m = fmaxf(red[0], 0.f);
    __syncthreads();

    const float e = (tid < NSELn) ? expf(l - m) : 0.f;
    red[tid] = e;
    __syncthreads();
    for (int s = 256; s > 0; s >>= 1) {
        if (tid < s) red[tid] += red[tid + s];
        __syncthreads();
    }
    const float e0  = expf(-m);
    const float inv = 1.f / (red[0] + e0);

    if (tid == 0) out[(size_t)b * (NSELn + 1)] = e0 * inv;
    if (tid < NSELn) out[(size_t)b * (NSELn + 1) + 1 + tid] = e * inv;
}

// ---------------------------------------------------------------------------
extern "C" void kernel_launch(void* const* d_in, const int* in_sizes, int n_in,
                              void* d_out, int out_size, void* d_ws, size_t ws_size,
                              hipStream_t stream)
{
    const float* obs    = (const float*)d_in[0];
    const float* la     = (const float*)d_in[1];
    const float* w_s1   = (const float*)d_in[2];
    const float* b_s1   = (const float*)d_in[3];
    const float* w_s2   = (const float*)d_in[4];
    const float* b_s2   = (const float*)d_in[5];
    const float* w_m1   = (const float*)d_in[6];
    const float* b_m1   = (const float*)d_in[7];
    const float* w_m2   = (const float*)d_in[8];
    const float* b_m2   = (const float*)d_in[9];
    const float* w_rel  = (const float*)d_in[10];
    const float* w_root = (const float*)d_in[11];
    const float* b_g    = (const float*)d_in[12];
    const float* w_fin  = (const float*)d_in[13];
    const float* b_fin  = (const float*)d_in[14];
    const int*   ei     = (const int*)d_in[15];
    const int*   et     = (const int*)d_in[16];
    const int*   sel    = (const int*)d_in[17];
    float*       out    = (float*)d_out;

    // workspace (bytes):
    //   region0: x (f32, 22,016,000 B) aliased with abar (half, same size)
    //            x dead after k_transpose; abar written by k_agg4.
    //   xTh: half, 11,008,000 B
    //   cnt/off/pos (4096 ints), csr (32000 ints), logitT (500*128 f32)
    char* wsb     = (char*)d_ws;
    float* x      = (float*)wsb;
    __half* abar  = (__half*)wsb;
    __half* xTh   = (__half*)(wsb + 22016000);
    int*   cnt    = (int*)(wsb + 33024000);
    int*   offb   = cnt + 4096;
    int*   pos    = offb + 4096;
    int*   csr    = pos + 4096;
    float* logitT = (float*)(csr + 32000);

    hipLaunchKernelGGL(k_zero,  dim3(16),  dim3(256), 0, stream, cnt, pos);
    hipLaunchKernelGGL(k_count, dim3((En + 255) / 256), dim3(256), 0, stream, ei, et, cnt);
    hipLaunchKernelGGL(k_scan,  dim3(1),   dim3(1024), 0, stream, cnt, offb);
    hipLaunchKernelGGL(k_fill,  dim3((En + 255) / 256), dim3(256), 0, stream, ei, et, offb, pos, csr);

    hipLaunchKernelGGL(k_temporal, dim3(Bn, (Nn + 63) / 64), dim3(512), 0, stream,
                       obs, w_s1, b_s1, w_s2, b_s2, w_m1, b_m1, w_m2, b_m2, x);

    hipLaunchKernelGGL(k_transpose, dim3((NFtot + 63) / 64), dim3(256), 0, stream, x, xTh);

    hipLaunchKernelGGL(k_agg4, dim3(NSELn * Rn), dim3(256), 0, stream,
                       xTh, csr, offb, cnt, sel, abar);

    hipLaunchKernelGGL(k_trans, dim3(NSELn), dim3(512), 0, stream,
                       xTh, abar, w_rel, w_root, b_g, w_fin, b_fin, la, sel, logitT);

    hipLaunchKernelGGL(k_softmax, dim3(Bn), dim3(512), 0, stream, logitT, out);
}

// Round 11
// 250.001 us; speedup vs baseline: 1.2661x; 1.2661x over previous
//
#include <hip/hip_runtime.h>
#include <hip/hip_fp16.h>
#include <math.h>

#define Bn 128
#define Nn 1000
#define Tn 50
#define En 32000
#define Rn 4
#define FSn 43
#define NSELn 500
#define NFtot (Nn * FSn)   // 43000

// ---------------------------------------------------------------------------
// Kernel 1: fused temporal features — R9 VERBATIM (measured 124 us, VGPR 60,
// zero spill). 512 thr = 8 waves, 64 nodes per block.
//   w0..w3: short conv quarter t[w*12,(w+1)*12) + long-max quarter
//   w4..w7: mid conv quarter of [0,30)
// Weights stay as plain global loads: both attempts to "improve" the weight
// path regressed (R7 restructure 186us, R10 LDS staging 203us).
// ---------------------------------------------------------------------------
__global__ __launch_bounds__(512) void k_temporal(
    const float* __restrict__ obs,
    const float* __restrict__ w_s1, const float* __restrict__ b_s1,
    const float* __restrict__ w_s2, const float* __restrict__ b_s2,
    const float* __restrict__ w_m1, const float* __restrict__ b_m1,
    const float* __restrict__ w_m2, const float* __restrict__ b_m2,
    float* __restrict__ x)
{
    __shared__ float lds[3 * 64 * 51];

    const int b     = blockIdx.x;
    const int tile0 = blockIdx.y * 64;
    const int tid   = threadIdx.x;
    const int lane  = tid & 63;
    const int w     = __builtin_amdgcn_readfirstlane(tid >> 6);   // 0..7
    const int nrows = (Nn - tile0) < 64 ? (Nn - tile0) : 64;

    for (int c = 0; c < 3; ++c) {
        const float* srcp = obs + ((size_t)(b * 3 + c) * Nn + tile0) * Tn;
        for (int idx = tid; idx < nrows * Tn; idx += 512) {
            const int r = idx / Tn;
            const int t = idx - r * Tn;
            lds[(c * 64 + r) * 51 + t] = srcp[idx];
        }
    }
    __syncthreads();

    float acc[20];
    float mx0 = -1e30f, mx1 = -1e30f, mx2 = -1e30f;

    if (w < 4) {
        // ---------------- short path: t in [w*12, w*12+12) ----------------
        #pragma unroll
        for (int o = 0; o < 20; ++o) acc[o] = (w == 0) ? b_s2[o] : 0.f;

        const float s10 = b_s1[0], s11 = b_s1[1], s12 = b_s1[2];
        const int t0 = w * 12;

        #pragma unroll 1
        for (int t = t0; t < t0 + 12; ++t) {
            float ov[9];
            #pragma unroll
            for (int c = 0; c < 3; ++c)
                #pragma unroll
                for (int d = 0; d < 3; ++d)
                    ov[c * 3 + d] = lds[(c * 64 + lane) * 51 + t + d];

            float v0 = s10, v1 = s11, v2 = s12;
            #pragma unroll
            for (int c = 0; c < 3; ++c) {
                v0 += ov[c * 3 + 0] * w_s1[(0 * 3 + c) * 3 + 0]
                    + ov[c * 3 + 1] * w_s1[(0 * 3 + c) * 3 + 1]
                    + ov[c * 3 + 2] * w_s1[(0 * 3 + c) * 3 + 2];
                v1 += ov[c * 3 + 0] * w_s1[(1 * 3 + c) * 3 + 0]
                    + ov[c * 3 + 1] * w_s1[(1 * 3 + c) * 3 + 1]
                    + ov[c * 3 + 2] * w_s1[(1 * 3 + c) * 3 + 2];
                v2 += ov[c * 3 + 0] * w_s1[(2 * 3 + c) * 3 + 0]
                    + ov[c * 3 + 1] * w_s1[(2 * 3 + c) * 3 + 1]
                    + ov[c * 3 + 2] * w_s1[(2 * 3 + c) * 3 + 2];
            }
            v0 = fmaxf(v0, 0.f); v1 = fmaxf(v1, 0.f); v2 = fmaxf(v2, 0.f);
            #pragma unroll
            for (int o = 0; o < 20; ++o) {
                acc[o] += v0 * w_s2[(o * 3 + 0) * 48 + t]
                        + v1 * w_s2[(o * 3 + 1) * 48 + t]
                        + v2 * w_s2[(o * 3 + 2) * 48 + t];
            }
        }

        // ---------------- long path quarter ----------------
        const int rb0 = (0 * 64 + lane) * 51;
        const int rb1 = (1 * 64 + lane) * 51;
        const int rb2 = (2 * 64 + lane) * 51;
        const int l0 = (w * 50) >> 2;
        const int l1 = ((w + 1) * 50) >> 2;
        #pragma unroll 1
        for (int t = l0; t < l1; ++t) {
            mx0 = fmaxf(mx0, lds[rb0 + t]);
            mx1 = fmaxf(mx1, lds[rb1 + t]);
            mx2 = fmaxf(mx2, lds[rb2 + t]);
        }
    } else {
        // ---------------- mid path: t in [m*30/4, (m+1)*30/4), m=w-4 --------
        #pragma unroll
        for (int o = 0; o < 20; ++o) acc[o] = (w == 4) ? b_m2[o] : 0.f;

        const float m10 = b_m1[0], m11 = b_m1[1], m12 = b_m1[2];
        const int m  = w - 4;
        const int t0 = (m * 30) >> 2;        // 0,7,15,22
        const int t1 = ((m + 1) * 30) >> 2;  // 7,15,22,30

        #pragma unroll 1
        for (int t = t0; t < t1; ++t) {
            float v0 = m10, v1 = m11, v2 = m12;
            #pragma unroll
            for (int c = 0; c < 3; ++c) {
                const int base = (c * 64 + lane) * 51 + t;
                #pragma unroll
                for (int d = 0; d < 21; ++d) {
                    const float ov = lds[base + d];
                    v0 += ov * w_m1[(0 * 3 + c) * 21 + d];
                    v1 += ov * w_m1[(1 * 3 + c) * 21 + d];
                    v2 += ov * w_m1[(2 * 3 + c) * 21 + d];
                }
            }
            v0 = fmaxf(v0, 0.f); v1 = fmaxf(v1, 0.f); v2 = fmaxf(v2, 0.f);
            #pragma unroll
            for (int o = 0; o < 20; ++o) {
                acc[o] += v0 * w_m2[(o * 3 + 0) * 30 + t]
                        + v1 * w_m2[(o * 3 + 1) * 30 + t]
                        + v2 * w_m2[(o * 3 + 2) * 30 + t];
            }
        }
    }

    // ---- exchange partials via the (now dead) obs tile ----
    __syncthreads();
    if (w >= 1 && w <= 3) {
        float* r = lds + (w - 1) * 1472 + lane;
        #pragma unroll
        for (int o = 0; o < 20; ++o) r[o * 64] = acc[o];
        r[20 * 64] = mx0;
        r[21 * 64] = mx1;
        r[22 * 64] = mx2;
    } else if (w >= 5) {
        float* r = lds + 4416 + (w - 5) * 1280 + lane;
        #pragma unroll
        for (int o = 0; o < 20; ++o) r[o * 64] = acc[o];
    }
    __syncthreads();

    if (lane < nrows) {
        float* xp = x + ((size_t)b * Nn + tile0 + lane) * FSn;
        if (w == 0) {
            #pragma unroll
            for (int o = 0; o < 20; ++o) {
                const int a = o * 64 + lane;
                xp[o] = fmaxf(acc[o] + lds[a] + lds[1472 + a] + lds[2944 + a], 0.f);
            }
            {
                const int a0 = 20 * 64 + lane, a1 = 21 * 64 + lane, a2 = 22 * 64 + lane;
                xp[40] = fmaxf(fmaxf(fmaxf(mx0, lds[a0]), fmaxf(lds[1472 + a0], lds[2944 + a0])), 0.f);
                xp[41] = fmaxf(fmaxf(fmaxf(mx1, lds[a1]), fmaxf(lds[1472 + a1], lds[2944 + a1])), 0.f);
                xp[42] = fmaxf(fmaxf(fmaxf(mx2, lds[a2]), fmaxf(lds[1472 + a2], lds[2944 + a2])), 0.f);
            }
        } else if (w == 4) {
            #pragma unroll
            for (int o = 0; o < 20; ++o) {
                const int a = 4416 + o * 64 + lane;
                xp[20 + o] = fmaxf(acc[o] + lds[a] + lds[a + 1280] + lds[a + 2560], 0.f);
            }
        }
    }
}

// ---------------------------------------------------------------------------
// Transpose + fp16 convert: x[b][nf] (f32) -> xT[nf][b] (f16)
// ---------------------------------------------------------------------------
__global__ __launch_bounds__(256) void k_transpose(const float* __restrict__ x,
                                                   __half* __restrict__ xT)
{
    __shared__ float tile[64][129];
    const int c0  = blockIdx.x * 64;
    const int tid = threadIdx.x;

    const int j  = tid & 63;
    const int bs = tid >> 6;
    for (int bb = bs; bb < Bn; bb += 4) {
        int c = c0 + j;
        if (c < NFtot) tile[j][bb] = x[(size_t)bb * NFtot + c];
    }
    __syncthreads();

    const int b  = tid & 127;
    for (int jj = (tid >> 7); jj < 64; jj += 2) {
        int c = c0 + jj;
        if (c < NFtot) xT[(size_t)c * Bn + b] = __float2half(tile[jj][b]);
    }
}

// ---------------------------------------------------------------------------
// CSR build
// ---------------------------------------------------------------------------
__global__ void k_zero(int* __restrict__ cnt, int* __restrict__ pos)
{
    int i = blockIdx.x * blockDim.x + threadIdx.x;
    if (i < 4096) { cnt[i] = 0; pos[i] = 0; }
}

__global__ void k_count(const int* __restrict__ ei, const int* __restrict__ et,
                        int* __restrict__ cnt)
{
    int e = blockIdx.x * blockDim.x + threadIdx.x;
    if (e < En) {
        int dst = ei[En + e];
        atomicAdd(&cnt[dst * Rn + et[e]], 1);
    }
}

__global__ __launch_bounds__(1024) void k_scan(const int* __restrict__ cnt,
                                               int* __restrict__ off)
{
    __shared__ int sums[1024];
    int tid = threadIdx.x;
    int base = tid * 4;
    int c[4];
    int ts = 0;
    #pragma unroll
    for (int k = 0; k < 4; ++k) {
        int i = base + k;
        c[k] = (i < Nn * Rn) ? cnt[i] : 0;
        ts += c[k];
    }
    sums[tid] = ts;
    __syncthreads();
    for (int d = 1; d < 1024; d <<= 1) {
        int t = 0;
        if (tid >= d) t = sums[tid - d];
        __syncthreads();
        sums[tid] += t;
        __syncthreads();
    }
    int excl = sums[tid] - ts;
    #pragma unroll
    for (int k = 0; k < 4; ++k) {
        int i = base + k;
        off[i] = excl;
        excl += c[k];
    }
}

__global__ void k_fill(const int* __restrict__ ei, const int* __restrict__ et,
                       const int* __restrict__ off, int* __restrict__ pos,
                       int* __restrict__ csr)
{
    int e = blockIdx.x * blockDim.x + threadIdx.x;
    if (e < En) {
        int src = ei[e];
        int dst = ei[En + e];
        int seg = dst * Rn + et[e];
        int p = atomicAdd(&pos[seg], 1);
        csr[off[seg] + p] = src;
    }
}

// ---------------------------------------------------------------------------
// Kernel 2a: per-(selected dst, relation) mean aggregation, fp16 in/out.
// grid = 500*4; 256 thr = 8 f-chunks x 32 b-quads (4 halves = 8B per load).
// ---------------------------------------------------------------------------
__global__ __launch_bounds__(256) void k_agg4(
    const __half* __restrict__ xT,
    const int* __restrict__ csr, const int* __restrict__ off,
    const int* __restrict__ cnt, const int* __restrict__ sel,
    __half* __restrict__ abar)
{
    __shared__ int srcs[128];

    const int blk = blockIdx.x;
    const int i   = blk >> 2;
    const int r   = blk & 3;
    const int dst = sel[i];
    const int tid = threadIdx.x;
    const int b4  = tid & 31;      // 4-halves group over b
    const int fc  = tid >> 5;      // 0..7

    const int seg = dst * Rn + r;
    const int c   = cnt[seg];
    const int o   = off[seg];
    const int cc  = (c < 128) ? c : 128;
    if (tid < cc) srcs[tid] = csr[o + tid];
    __syncthreads();

    const int nk = (fc < 3) ? 6 : 5;   // f = fc + 8k < 43

    float4 acc[6];
    #pragma unroll
    for (int k = 0; k < 6; ++k) acc[k] = make_float4(0.f, 0.f, 0.f, 0.f);

    const float2* xT2 = (const float2*)xT;   // 1 float2 = 4 halves
    for (int j = 0; j < cc; ++j) {
        const int src = srcs[j];
        const float2* base = xT2 + (size_t)src * (FSn * 32) + (size_t)fc * 32 + b4;
        #pragma unroll
        for (int k = 0; k < 6; ++k) {
            if (k < nk) {
                float2 raw = base[k * 8 * 32];
                const __half2 h0 = ((const __half2*)&raw)[0];
                const __half2 h1 = ((const __half2*)&raw)[1];
                const float2 f0 = __half22float2(h0);
                const float2 f1 = __half22float2(h1);
                acc[k].x += f0.x; acc[k].y += f0.y;
                acc[k].z += f1.x; acc[k].w += f1.y;
            }
        }
    }

    const float inv = (c > 0) ? 1.f / (float)c : 0.f;
    float2* ab2 = (float2*)abar + (size_t)(i * Rn + r) * (FSn * 32) + (size_t)fc * 32 + b4;
    #pragma unroll
    for (int k = 0; k < 6; ++k) {
        if (k < nk) {
            float2 st;
            ((__half2*)&st)[0] = __floats2half2_rn(acc[k].x * inv, acc[k].y * inv);
            ((__half2*)&st)[1] = __floats2half2_rn(acc[k].z * inv, acc[k].w * inv);
            ab2[k * 8 * 32] = st;
        }
    }
}

// ---------------------------------------------------------------------------
// Kernel 2b: relational transform + root + leaky + final projection.
// grid = 500; 512 thr = 4 f-groups x 128 b. Reads abar(half) + xT(half).
// ---------------------------------------------------------------------------
__global__ __launch_bounds__(512) void k_trans(
    const __half* __restrict__ xT, const __half* __restrict__ abar,
    const float* __restrict__ w_rel, const float* __restrict__ w_root,
    const float* __restrict__ b_g,
    const float* __restrict__ w_fin, const float* __restrict__ b_fin,
    const float* __restrict__ la,
    const int* __restrict__ sel,
    float* __restrict__ logitT)
{
    __shared__ float red[FSn + 1][Bn];

    const int i   = blockIdx.x;
    const int dst = sel[i];
    const int tid = threadIdx.x;
    const int fs  = tid >> 7;
    const int b   = tid & 127;

    const int f0 = fs * 11;
    const int nf = (fs == 3) ? 10 : 11;

    float a[5][11];
    #pragma unroll
    for (int rr = 0; rr < 4; ++rr) {
        const __half* ap = abar + ((size_t)(i * Rn + rr) * FSn + f0) * Bn + b;
        #pragma unroll
        for (int k = 0; k < 11; ++k)
            a[rr][k] = (k < nf) ? __half2float(ap[(size_t)k * Bn]) : 0.f;
    }
    {
        const __half* xp = xT + ((size_t)dst * FSn + f0) * Bn + b;
        #pragma unroll
        for (int k = 0; k < 11; ++k)
            a[4][k] = (k < nf) ? __half2float(xp[(size_t)k * Bn]) : 0.f;
    }

    float accg[FSn];
    #pragma unroll
    for (int g = 0; g < FSn; ++g) accg[g] = 0.f;
    float psum = 0.f;

    #pragma unroll
    for (int k = 0; k < 11; ++k) {
        if (k < nf) {
            const int f = f0 + k;
            #pragma unroll
            for (int rr = 0; rr < 5; ++rr) {
                const float av = a[rr][k];
                const float* wrow = (rr < 4)
                    ? (w_rel + ((size_t)rr * FSn + f) * FSn)
                    : (w_root + (size_t)f * FSn);
                #pragma unroll
                for (int g = 0; g < FSn; ++g) accg[g] += av * wrow[g];
            }
            psum += a[4][k] * w_fin[1 + f];
        }
    }

    if (fs == 3) {
        #pragma unroll
        for (int g = 0; g < FSn; ++g) red[g][b] = accg[g];
        red[FSn][b] = psum;
    }
    __syncthreads();
    if (fs == 2) {
        #pragma unroll
        for (int g = 0; g < FSn; ++g) red[g][b] += accg[g];
        red[FSn][b] += psum;
    }
    __syncthreads();
    if (fs == 1) {
        #pragma unroll
        for (int g = 0; g < FSn; ++g) red[g][b] += accg[g];
        red[FSn][b] += psum;
    }
    __syncthreads();
    if (fs == 0) {
        float logit = b_fin[0] + w_fin[0] * la[(size_t)b * (NSELn + 1) + 1 + i]
                    + psum + red[FSn][b];
        #pragma unroll
        for (int g = 0; g < FSn; ++g) {
            float v = accg[g] + red[g][b] + b_g[g];
            v = (v > 0.f) ? v : 0.01f * v;
            logit += v * w_fin[44 + g];
        }
        logitT[(size_t)i * Bn + b] = logit;
    }
}

// ---------------------------------------------------------------------------
// Kernel 3: softmax over [0, logits(500)] per batch. Block per b.
// ---------------------------------------------------------------------------
__global__ __launch_bounds__(512) void k_softmax(const float* __restrict__ logitT,
                                                 float* __restrict__ out)
{
    __shared__ float red[512];
    const int b   = blockIdx.x;
    const int tid = threadIdx.x;

    const float l = (tid < NSELn) ? logitT[(size_t)tid * Bn + b] : -1e30f;
    red[tid] = l;
    __syncthreads();
    for (int s = 256; s > 0; s >>= 1) {
        if (tid < s) red[tid] = fmaxf(red[tid], red[tid + s]);
        __syncthreads();
    }
    const float m = fmaxf(red[0], 0.f);
    __syncthreads();

    const float e = (tid < NSELn) ? expf(l - m) : 0.f;
    red[tid] = e;
    __syncthreads();
    for (int s = 256; s > 0; s >>= 1) {
        if (tid < s) red[tid] += red[tid + s];
        __syncthreads();
    }
    const float e0  = expf(-m);
    const float inv = 1.f / (red[0] + e0);

    if (tid == 0) out[(size_t)b * (NSELn + 1)] = e0 * inv;
    if (tid < NSELn) out[(size_t)b * (NSELn + 1) + 1 + tid] = e * inv;
}

// ---------------------------------------------------------------------------
extern "C" void kernel_launch(void* const* d_in, const int* in_sizes, int n_in,
                              void* d_out, int out_size, void* d_ws, size_t ws_size,
                              hipStream_t stream)
{
    const float* obs    = (const float*)d_in[0];
    const float* la     = (const float*)d_in[1];
    const float* w_s1   = (const float*)d_in[2];
    const float* b_s1   = (const float*)d_in[3];
    const float* w_s2   = (const float*)d_in[4];
    const float* b_s2   = (const float*)d_in[5];
    const float* w_m1   = (const float*)d_in[6];
    const float* b_m1   = (const float*)d_in[7];
    const float* w_m2   = (const float*)d_in[8];
    const float* b_m2   = (const float*)d_in[9];
    const float* w_rel  = (const float*)d_in[10];
    const float* w_root = (const float*)d_in[11];
    const float* b_g    = (const float*)d_in[12];
    const float* w_fin  = (const float*)d_in[13];
    const float* b_fin  = (const float*)d_in[14];
    const int*   ei     = (const int*)d_in[15];
    const int*   et     = (const int*)d_in[16];
    const int*   sel    = (const int*)d_in[17];
    float*       out    = (float*)d_out;

    // workspace (bytes):
    //   region0: x (f32, 22,016,000 B) aliased with abar (half, same size)
    //            x dead after k_transpose; abar written by k_agg4.
    //   xTh: half, 11,008,000 B
    //   cnt/off/pos (4096 ints), csr (32000 ints), logitT (500*128 f32)
    char* wsb     = (char*)d_ws;
    float* x      = (float*)wsb;
    __half* abar  = (__half*)wsb;
    __half* xTh   = (__half*)(wsb + 22016000);
    int*   cnt    = (int*)(wsb + 33024000);
    int*   offb   = cnt + 4096;
    int*   pos    = offb + 4096;
    int*   csr    = pos + 4096;
    float* logitT = (float*)(csr + 32000);

    hipLaunchKernelGGL(k_zero,  dim3(16),  dim3(256), 0, stream, cnt, pos);
    hipLaunchKernelGGL(k_count, dim3((En + 255) / 256), dim3(256), 0, stream, ei, et, cnt);
    hipLaunchKernelGGL(k_scan,  dim3(1),   dim3(1024), 0, stream, cnt, offb);
    hipLaunchKernelGGL(k_fill,  dim3((En + 255) / 256), dim3(256), 0, stream, ei, et, offb, pos, csr);

    hipLaunchKernelGGL(k_temporal, dim3(Bn, (Nn + 63) / 64), dim3(512), 0, stream,
                       obs, w_s1, b_s1, w_s2, b_s2, w_m1, b_m1, w_m2, b_m2, x);

    hipLaunchKernelGGL(k_transpose, dim3((NFtot + 63) / 64), dim3(256), 0, stream, x, xTh);

    hipLaunchKernelGGL(k_agg4, dim3(NSELn * Rn), dim3(256), 0, stream,
                       xTh, csr, offb, cnt, sel, abar);

    hipLaunchKernelGGL(k_trans, dim3(NSELn), dim3(512), 0, stream,
                       xTh, abar, w_rel, w_root, b_g, w_fin, b_fin, la, sel, logitT);

    hipLaunchKernelGGL(k_softmax, dim3(Bn), dim3(512), 0, stream, logitT, out);
}

// Round 12
// 239.583 us; speedup vs baseline: 1.3211x; 1.0435x over previous
//
#include <hip/hip_runtime.h>
#include <hip/hip_fp16.h>
#include <math.h>

#define Bn 128
#define Nn 1000
#define Tn 50
#define En 32000
#define Rn 4
#define FSn 43
#define NSELn 500
#define NFtot (Nn * FSn)   // 43000

// ---------------------------------------------------------------------------
// Kernel 1: fused temporal features. 512 thr = 8 waves, 64 nodes per block.
// R9's loop bodies VERBATIM (only measured-good codegen: VGPR 60, no spill),
// with the role split rebalanced for mid's heavier per-t cost (252 vs 90 VALU):
//   w0..w2: short conv t[w*16,(w+1)*16)  + long-max third   (~1440+51 ops)
//   w3..w7: mid conv t[(w-3)*6,(w-3)*6+6)                    (~1512 ops)
// (R10 had this split but regressed from its LDS weight staging; this keeps
// weights as plain global loads.)
// ---------------------------------------------------------------------------
__global__ __launch_bounds__(512) void k_temporal(
    const float* __restrict__ obs,
    const float* __restrict__ w_s1, const float* __restrict__ b_s1,
    const float* __restrict__ w_s2, const float* __restrict__ b_s2,
    const float* __restrict__ w_m1, const float* __restrict__ b_m1,
    const float* __restrict__ w_m2, const float* __restrict__ b_m2,
    float* __restrict__ x)
{
    __shared__ float lds[3 * 64 * 51];

    const int b     = blockIdx.x;
    const int tile0 = blockIdx.y * 64;
    const int tid   = threadIdx.x;
    const int lane  = tid & 63;
    const int w     = __builtin_amdgcn_readfirstlane(tid >> 6);   // 0..7
    const int nrows = (Nn - tile0) < 64 ? (Nn - tile0) : 64;

    for (int c = 0; c < 3; ++c) {
        const float* srcp = obs + ((size_t)(b * 3 + c) * Nn + tile0) * Tn;
        for (int idx = tid; idx < nrows * Tn; idx += 512) {
            const int r = idx / Tn;
            const int t = idx - r * Tn;
            lds[(c * 64 + r) * 51 + t] = srcp[idx];
        }
    }
    __syncthreads();

    float acc[20];
    float mx0 = -1e30f, mx1 = -1e30f, mx2 = -1e30f;

    if (w < 3) {
        // ---------------- short path: t in [w*16, w*16+16) ----------------
        #pragma unroll
        for (int o = 0; o < 20; ++o) acc[o] = (w == 0) ? b_s2[o] : 0.f;

        const float s10 = b_s1[0], s11 = b_s1[1], s12 = b_s1[2];
        const int t0 = w * 16;

        #pragma unroll 1
        for (int t = t0; t < t0 + 16; ++t) {
            float ov[9];
            #pragma unroll
            for (int c = 0; c < 3; ++c)
                #pragma unroll
                for (int d = 0; d < 3; ++d)
                    ov[c * 3 + d] = lds[(c * 64 + lane) * 51 + t + d];

            float v0 = s10, v1 = s11, v2 = s12;
            #pragma unroll
            for (int c = 0; c < 3; ++c) {
                v0 += ov[c * 3 + 0] * w_s1[(0 * 3 + c) * 3 + 0]
                    + ov[c * 3 + 1] * w_s1[(0 * 3 + c) * 3 + 1]
                    + ov[c * 3 + 2] * w_s1[(0 * 3 + c) * 3 + 2];
                v1 += ov[c * 3 + 0] * w_s1[(1 * 3 + c) * 3 + 0]
                    + ov[c * 3 + 1] * w_s1[(1 * 3 + c) * 3 + 1]
                    + ov[c * 3 + 2] * w_s1[(1 * 3 + c) * 3 + 2];
                v2 += ov[c * 3 + 0] * w_s1[(2 * 3 + c) * 3 + 0]
                    + ov[c * 3 + 1] * w_s1[(2 * 3 + c) * 3 + 1]
                    + ov[c * 3 + 2] * w_s1[(2 * 3 + c) * 3 + 2];
            }
            v0 = fmaxf(v0, 0.f); v1 = fmaxf(v1, 0.f); v2 = fmaxf(v2, 0.f);
            #pragma unroll
            for (int o = 0; o < 20; ++o) {
                acc[o] += v0 * w_s2[(o * 3 + 0) * 48 + t]
                        + v1 * w_s2[(o * 3 + 1) * 48 + t]
                        + v2 * w_s2[(o * 3 + 2) * 48 + t];
            }
        }

        // ---------------- long path third ----------------
        const int rb0 = (0 * 64 + lane) * 51;
        const int rb1 = (1 * 64 + lane) * 51;
        const int rb2 = (2 * 64 + lane) * 51;
        const int l0 = (w == 0) ? 0 : (w == 1) ? 17 : 34;
        const int l1 = (w == 0) ? 17 : (w == 1) ? 34 : 50;
        #pragma unroll 1
        for (int t = l0; t < l1; ++t) {
            mx0 = fmaxf(mx0, lds[rb0 + t]);
            mx1 = fmaxf(mx1, lds[rb1 + t]);
            mx2 = fmaxf(mx2, lds[rb2 + t]);
        }
    } else {
        // ---------------- mid path: t in [(w-3)*6, (w-3)*6+6) --------------
        #pragma unroll
        for (int o = 0; o < 20; ++o) acc[o] = (w == 3) ? b_m2[o] : 0.f;

        const float m10 = b_m1[0], m11 = b_m1[1], m12 = b_m1[2];
        const int t0 = (w - 3) * 6;

        #pragma unroll 1
        for (int t = t0; t < t0 + 6; ++t) {
            float v0 = m10, v1 = m11, v2 = m12;
            #pragma unroll
            for (int c = 0; c < 3; ++c) {
                const int base = (c * 64 + lane) * 51 + t;
                #pragma unroll
                for (int d = 0; d < 21; ++d) {
                    const float ov = lds[base + d];
                    v0 += ov * w_m1[(0 * 3 + c) * 21 + d];
                    v1 += ov * w_m1[(1 * 3 + c) * 21 + d];
                    v2 += ov * w_m1[(2 * 3 + c) * 21 + d];
                }
            }
            v0 = fmaxf(v0, 0.f); v1 = fmaxf(v1, 0.f); v2 = fmaxf(v2, 0.f);
            #pragma unroll
            for (int o = 0; o < 20; ++o) {
                acc[o] += v0 * w_m2[(o * 3 + 0) * 30 + t]
                        + v1 * w_m2[(o * 3 + 1) * 30 + t]
                        + v2 * w_m2[(o * 3 + 2) * 30 + t];
            }
        }
    }

    // ---- exchange partials via the (now dead) obs tile ----
    // waves 1,2  -> [23][64] at (w-1)*1472  (20 short + 3 long rows)
    // waves 4..7 -> [20][64] at 2944 + (w-4)*1280
    __syncthreads();
    if (w == 1 || w == 2) {
        float* r = lds + (w - 1) * 1472 + lane;
        #pragma unroll
        for (int o = 0; o < 20; ++o) r[o * 64] = acc[o];
        r[20 * 64] = mx0;
        r[21 * 64] = mx1;
        r[22 * 64] = mx2;
    } else if (w >= 4) {
        float* r = lds + 2944 + (w - 4) * 1280 + lane;
        #pragma unroll
        for (int o = 0; o < 20; ++o) r[o * 64] = acc[o];
    }
    __syncthreads();

    if (lane < nrows) {
        float* xp = x + ((size_t)b * Nn + tile0 + lane) * FSn;
        if (w == 0) {
            #pragma unroll
            for (int o = 0; o < 20; ++o) {
                const int a = o * 64 + lane;
                xp[o] = fmaxf(acc[o] + lds[a] + lds[1472 + a], 0.f);
            }
            {
                const int a0 = 20 * 64 + lane, a1 = 21 * 64 + lane, a2 = 22 * 64 + lane;
                xp[40] = fmaxf(fmaxf(mx0, fmaxf(lds[a0], lds[1472 + a0])), 0.f);
                xp[41] = fmaxf(fmaxf(mx1, fmaxf(lds[a1], lds[1472 + a1])), 0.f);
                xp[42] = fmaxf(fmaxf(mx2, fmaxf(lds[a2], lds[1472 + a2])), 0.f);
            }
        } else if (w == 3) {
            #pragma unroll
            for (int o = 0; o < 20; ++o) {
                const int a = 2944 + o * 64 + lane;
                xp[20 + o] = fmaxf(acc[o] + lds[a] + lds[a + 1280]
                                          + lds[a + 2560] + lds[a + 3840], 0.f);
            }
        }
    }
}

// ---------------------------------------------------------------------------
// Transpose + fp16 convert: x[b][nf] (f32) -> xT[nf][b] (f16)
// ---------------------------------------------------------------------------
__global__ __launch_bounds__(256) void k_transpose(const float* __restrict__ x,
                                                   __half* __restrict__ xT)
{
    __shared__ float tile[64][129];
    const int c0  = blockIdx.x * 64;
    const int tid = threadIdx.x;

    const int j  = tid & 63;
    const int bs = tid >> 6;
    for (int bb = bs; bb < Bn; bb += 4) {
        int c = c0 + j;
        if (c < NFtot) tile[j][bb] = x[(size_t)bb * NFtot + c];
    }
    __syncthreads();

    const int b  = tid & 127;
    for (int jj = (tid >> 7); jj < 64; jj += 2) {
        int c = c0 + jj;
        if (c < NFtot) xT[(size_t)c * Bn + b] = __float2half(tile[jj][b]);
    }
}

// ---------------------------------------------------------------------------
// CSR build
// ---------------------------------------------------------------------------
__global__ void k_zero(int* __restrict__ cnt, int* __restrict__ pos)
{
    int i = blockIdx.x * blockDim.x + threadIdx.x;
    if (i < 4096) { cnt[i] = 0; pos[i] = 0; }
}

__global__ void k_count(const int* __restrict__ ei, const int* __restrict__ et,
                        int* __restrict__ cnt)
{
    int e = blockIdx.x * blockDim.x + threadIdx.x;
    if (e < En) {
        int dst = ei[En + e];
        atomicAdd(&cnt[dst * Rn + et[e]], 1);
    }
}

__global__ __launch_bounds__(1024) void k_scan(const int* __restrict__ cnt,
                                               int* __restrict__ off)
{
    __shared__ int sums[1024];
    int tid = threadIdx.x;
    int base = tid * 4;
    int c[4];
    int ts = 0;
    #pragma unroll
    for (int k = 0; k < 4; ++k) {
        int i = base + k;
        c[k] = (i < Nn * Rn) ? cnt[i] : 0;
        ts += c[k];
    }
    sums[tid] = ts;
    __syncthreads();
    for (int d = 1; d < 1024; d <<= 1) {
        int t = 0;
        if (tid >= d) t = sums[tid - d];
        __syncthreads();
        sums[tid] += t;
        __syncthreads();
    }
    int excl = sums[tid] - ts;
    #pragma unroll
    for (int k = 0; k < 4; ++k) {
        int i = base + k;
        off[i] = excl;
        excl += c[k];
    }
}

__global__ void k_fill(const int* __restrict__ ei, const int* __restrict__ et,
                       const int* __restrict__ off, int* __restrict__ pos,
                       int* __restrict__ csr)
{
    int e = blockIdx.x * blockDim.x + threadIdx.x;
    if (e < En) {
        int src = ei[e];
        int dst = ei[En + e];
        int seg = dst * Rn + et[e];
        int p = atomicAdd(&pos[seg], 1);
        csr[off[seg] + p] = src;
    }
}

// ---------------------------------------------------------------------------
// Kernel 2a: per-(selected dst, relation) mean aggregation, fp16 in/out.
// grid = 500*4; 256 thr = 8 f-chunks x 32 b-quads (4 halves = 8B per load).
// ---------------------------------------------------------------------------
__global__ __launch_bounds__(256) void k_agg4(
    const __half* __restrict__ xT,
    const int* __restrict__ csr, const int* __restrict__ off,
    const int* __restrict__ cnt, const int* __restrict__ sel,
    __half* __restrict__ abar)
{
    __shared__ int srcs[128];

    const int blk = blockIdx.x;
    const int i   = blk >> 2;
    const int r   = blk & 3;
    const int dst = sel[i];
    const int tid = threadIdx.x;
    const int b4  = tid & 31;      // 4-halves group over b
    const int fc  = tid >> 5;      // 0..7

    const int seg = dst * Rn + r;
    const int c   = cnt[seg];
    const int o   = off[seg];
    const int cc  = (c < 128) ? c : 128;
    if (tid < cc) srcs[tid] = csr[o + tid];
    __syncthreads();

    const int nk = (fc < 3) ? 6 : 5;   // f = fc + 8k < 43

    float4 acc[6];
    #pragma unroll
    for (int k = 0; k < 6; ++k) acc[k] = make_float4(0.f, 0.f, 0.f, 0.f);

    const float2* xT2 = (const float2*)xT;   // 1 float2 = 4 halves
    for (int j = 0; j < cc; ++j) {
        const int src = srcs[j];
        const float2* base = xT2 + (size_t)src * (FSn * 32) + (size_t)fc * 32 + b4;
        #pragma unroll
        for (int k = 0; k < 6; ++k) {
            if (k < nk) {
                float2 raw = base[k * 8 * 32];
                const __half2 h0 = ((const __half2*)&raw)[0];
                const __half2 h1 = ((const __half2*)&raw)[1];
                const float2 f0 = __half22float2(h0);
                const float2 f1 = __half22float2(h1);
                acc[k].x += f0.x; acc[k].y += f0.y;
                acc[k].z += f1.x; acc[k].w += f1.y;
            }
        }
    }

    const float inv = (c > 0) ? 1.f / (float)c : 0.f;
    float2* ab2 = (float2*)abar + (size_t)(i * Rn + r) * (FSn * 32) + (size_t)fc * 32 + b4;
    #pragma unroll
    for (int k = 0; k < 6; ++k) {
        if (k < nk) {
            float2 st;
            ((__half2*)&st)[0] = __floats2half2_rn(acc[k].x * inv, acc[k].y * inv);
            ((__half2*)&st)[1] = __floats2half2_rn(acc[k].z * inv, acc[k].w * inv);
            ab2[k * 8 * 32] = st;
        }
    }
}

// ---------------------------------------------------------------------------
// Kernel 2b: relational transform + root + leaky + final projection.
// grid = 500; 512 thr = 4 f-groups x 128 b. Reads abar(half) + xT(half).
// ---------------------------------------------------------------------------
__global__ __launch_bounds__(512) void k_trans(
    const __half* __restrict__ xT, const __half* __restrict__ abar,
    const float* __restrict__ w_rel, const float* __restrict__ w_root,
    const float* __restrict__ b_g,
    const float* __restrict__ w_fin, const float* __restrict__ b_fin,
    const float* __restrict__ la,
    const int* __restrict__ sel,
    float* __restrict__ logitT)
{
    __shared__ float red[FSn + 1][Bn];

    const int i   = blockIdx.x;
    const int dst = sel[i];
    const int tid = threadIdx.x;
    const int fs  = tid >> 7;
    const int b   = tid & 127;

    const int f0 = fs * 11;
    const int nf = (fs == 3) ? 10 : 11;

    float a[5][11];
    #pragma unroll
    for (int rr = 0; rr < 4; ++rr) {
        const __half* ap = abar + ((size_t)(i * Rn + rr) * FSn + f0) * Bn + b;
        #pragma unroll
        for (int k = 0; k < 11; ++k)
            a[rr][k] = (k < nf) ? __half2float(ap[(size_t)k * Bn]) : 0.f;
    }
    {
        const __half* xp = xT + ((size_t)dst * FSn + f0) * Bn + b;
        #pragma unroll
        for (int k = 0; k < 11; ++k)
            a[4][k] = (k < nf) ? __half2float(xp[(size_t)k * Bn]) : 0.f;
    }

    float accg[FSn];
    #pragma unroll
    for (int g = 0; g < FSn; ++g) accg[g] = 0.f;
    float psum = 0.f;

    #pragma unroll
    for (int k = 0; k < 11; ++k) {
        if (k < nf) {
            const int f = f0 + k;
            #pragma unroll
            for (int rr = 0; rr < 5; ++rr) {
                const float av = a[rr][k];
                const float* wrow = (rr < 4)
                    ? (w_rel + ((size_t)rr * FSn + f) * FSn)
                    : (w_root + (size_t)f * FSn);
                #pragma unroll
                for (int g = 0; g < FSn; ++g) accg[g] += av * wrow[g];
            }
            psum += a[4][k] * w_fin[1 + f];
        }
    }

    if (fs == 3) {
        #pragma unroll
        for (int g = 0; g < FSn; ++g) red[g][b] = accg[g];
        red[FSn][b] = psum;
    }
    __syncthreads();
    if (fs == 2) {
        #pragma unroll
        for (int g = 0; g < FSn; ++g) red[g][b] += accg[g];
        red[FSn][b] += psum;
    }
    __syncthreads();
    if (fs == 1) {
        #pragma unroll
        for (int g = 0; g < FSn; ++g) red[g][b] += accg[g];
        red[FSn][b] += psum;
    }
    __syncthreads();
    if (fs == 0) {
        float logit = b_fin[0] + w_fin[0] * la[(size_t)b * (NSELn + 1) + 1 + i]
                    + psum + red[FSn][b];
        #pragma unroll
        for (int g = 0; g < FSn; ++g) {
            float v = accg[g] + red[g][b] + b_g[g];
            v = (v > 0.f) ? v : 0.01f * v;
            logit += v * w_fin[44 + g];
        }
        logitT[(size_t)i * Bn + b] = logit;
    }
}

// ---------------------------------------------------------------------------
// Kernel 3: softmax over [0, logits(500)] per batch. Block per b.
// ---------------------------------------------------------------------------
__global__ __launch_bounds__(512) void k_softmax(const float* __restrict__ logitT,
                                                 float* __restrict__ out)
{
    __shared__ float red[512];
    const int b   = blockIdx.x;
    const int tid = threadIdx.x;

    const float l = (tid < NSELn) ? logitT[(size_t)tid * Bn + b] : -1e30f;
    red[tid] = l;
    __syncthreads();
    for (int s = 256; s > 0; s >>= 1) {
        if (tid < s) red[tid] = fmaxf(red[tid], red[tid + s]);
        __syncthreads();
    }
    const float m = fmaxf(red[0], 0.f);
    __syncthreads();

    const float e = (tid < NSELn) ? expf(l - m) : 0.f;
    red[tid] = e;
    __syncthreads();
    for (int s = 256; s > 0; s >>= 1) {
        if (tid < s) red[tid] += red[tid + s];
        __syncthreads();
    }
    const float e0  = expf(-m);
    const float inv = 1.f / (red[0] + e0);

    if (tid == 0) out[(size_t)b * (NSELn + 1)] = e0 * inv;
    if (tid < NSELn) out[(size_t)b * (NSELn + 1) + 1 + tid] = e * inv;
}

// ---------------------------------------------------------------------------
extern "C" void kernel_launch(void* const* d_in, const int* in_sizes, int n_in,
                              void* d_out, int out_size, void* d_ws, size_t ws_size,
                              hipStream_t stream)
{
    const float* obs    = (const float*)d_in[0];
    const float* la     = (const float*)d_in[1];
    const float* w_s1   = (const float*)d_in[2];
    const float* b_s1   = (const float*)d_in[3];
    const float* w_s2   = (const float*)d_in[4];
    const float* b_s2   = (const float*)d_in[5];
    const float* w_m1   = (const float*)d_in[6];
    const float* b_m1   = (const float*)d_in[7];
    const float* w_m2   = (const float*)d_in[8];
    const float* b_m2   = (const float*)d_in[9];
    const float* w_rel  = (const float*)d_in[10];
    const float* w_root = (const float*)d_in[11];
    const float* b_g    = (const float*)d_in[12];
    const float* w_fin  = (const float*)d_in[13];
    const float* b_fin  = (const float*)d_in[14];
    const int*   ei     = (const int*)d_in[15];
    const int*   et     = (const int*)d_in[16];
    const int*   sel    = (const int*)d_in[17];
    float*       out    = (float*)d_out;

    // workspace (bytes):
    //   region0: x (f32, 22,016,000 B) aliased with abar (half, same size)
    //   xTh: half, 11,008,000 B
    //   cnt/off/pos (4096 ints), csr (32000 ints), logitT (500*128 f32)
    char* wsb     = (char*)d_ws;
    float* x      = (float*)wsb;
    __half* abar  = (__half*)wsb;
    __half* xTh   = (__half*)(wsb + 22016000);
    int*   cnt    = (int*)(wsb + 33024000);
    int*   offb   = cnt + 4096;
    int*   pos    = offb + 4096;
    int*   csr    = pos + 4096;
    float* logitT = (float*)(csr + 32000);

    hipLaunchKernelGGL(k_zero,  dim3(16),  dim3(256), 0, stream, cnt, pos);
    hipLaunchKernelGGL(k_count, dim3((En + 255) / 256), dim3(256), 0, stream, ei, et, cnt);
    hipLaunchKernelGGL(k_scan,  dim3(1),   dim3(1024), 0, stream, cnt, offb);
    hipLaunchKernelGGL(k_fill,  dim3((En + 255) / 256), dim3(256), 0, stream, ei, et, offb, pos, csr);

    hipLaunchKernelGGL(k_temporal, dim3(Bn, (Nn + 63) / 64), dim3(512), 0, stream,
                       obs, w_s1, b_s1, w_s2, b_s2, w_m1, b_m1, w_m2, b_m2, x);

    hipLaunchKernelGGL(k_transpose, dim3((NFtot + 63) / 64), dim3(256), 0, stream, x, xTh);

    hipLaunchKernelGGL(k_agg4, dim3(NSELn * Rn), dim3(256), 0, stream,
                       xTh, csr, offb, cnt, sel, abar);

    hipLaunchKernelGGL(k_trans, dim3(NSELn), dim3(512), 0, stream,
                       xTh, abar, w_rel, w_root, b_g, w_fin, b_fin, la, sel, logitT);

    hipLaunchKernelGGL(k_softmax, dim3(Bn), dim3(512), 0, stream, logitT, out);
}

// Round 13
// 235.886 us; speedup vs baseline: 1.3419x; 1.0157x over previous
//
#include <hip/hip_runtime.h>
#include <hip/hip_fp16.h>
#include <math.h>

#define Bn 128
#define Nn 1000
#define Tn 50
#define En 32000
#define Rn 4
#define FSn 43
#define NSELn 500
#define NFtot (Nn * FSn)   // 43000

// ---------------------------------------------------------------------------
// Kernel 1: fused temporal features. 512 thr = 8 waves, 64 nodes per block.
// R12 structure; ONLY change: mid conv1 accumulation split per-channel
// (9 independent 21-deep FMA chains instead of 3x 63-deep; dep 84 cyc < issue
// ~126 cyc/t so the chain stall disappears even at ~3 waves/SIMD).
//   w0..w2: short conv t[w*16,(w+1)*16) + long-max third
//   w3..w7: mid conv t[(w-3)*6,(w-3)*6+6)
// ---------------------------------------------------------------------------
__global__ __launch_bounds__(512) void k_temporal(
    const float* __restrict__ obs,
    const float* __restrict__ w_s1, const float* __restrict__ b_s1,
    const float* __restrict__ w_s2, const float* __restrict__ b_s2,
    const float* __restrict__ w_m1, const float* __restrict__ b_m1,
    const float* __restrict__ w_m2, const float* __restrict__ b_m2,
    float* __restrict__ x)
{
    __shared__ float lds[3 * 64 * 51];

    const int b     = blockIdx.x;
    const int tile0 = blockIdx.y * 64;
    const int tid   = threadIdx.x;
    const int lane  = tid & 63;
    const int w     = __builtin_amdgcn_readfirstlane(tid >> 6);   // 0..7
    const int nrows = (Nn - tile0) < 64 ? (Nn - tile0) : 64;

    for (int c = 0; c < 3; ++c) {
        const float* srcp = obs + ((size_t)(b * 3 + c) * Nn + tile0) * Tn;
        for (int idx = tid; idx < nrows * Tn; idx += 512) {
            const int r = idx / Tn;
            const int t = idx - r * Tn;
            lds[(c * 64 + r) * 51 + t] = srcp[idx];
        }
    }
    __syncthreads();

    float acc[20];
    float mx0 = -1e30f, mx1 = -1e30f, mx2 = -1e30f;

    if (w < 3) {
        // ---------------- short path: t in [w*16, w*16+16) ----------------
        #pragma unroll
        for (int o = 0; o < 20; ++o) acc[o] = (w == 0) ? b_s2[o] : 0.f;

        const float s10 = b_s1[0], s11 = b_s1[1], s12 = b_s1[2];
        const int t0 = w * 16;

        #pragma unroll 1
        for (int t = t0; t < t0 + 16; ++t) {
            float ov[9];
            #pragma unroll
            for (int c = 0; c < 3; ++c)
                #pragma unroll
                for (int d = 0; d < 3; ++d)
                    ov[c * 3 + d] = lds[(c * 64 + lane) * 51 + t + d];

            float v0 = s10, v1 = s11, v2 = s12;
            #pragma unroll
            for (int c = 0; c < 3; ++c) {
                v0 += ov[c * 3 + 0] * w_s1[(0 * 3 + c) * 3 + 0]
                    + ov[c * 3 + 1] * w_s1[(0 * 3 + c) * 3 + 1]
                    + ov[c * 3 + 2] * w_s1[(0 * 3 + c) * 3 + 2];
                v1 += ov[c * 3 + 0] * w_s1[(1 * 3 + c) * 3 + 0]
                    + ov[c * 3 + 1] * w_s1[(1 * 3 + c) * 3 + 1]
                    + ov[c * 3 + 2] * w_s1[(1 * 3 + c) * 3 + 2];
                v2 += ov[c * 3 + 0] * w_s1[(2 * 3 + c) * 3 + 0]
                    + ov[c * 3 + 1] * w_s1[(2 * 3 + c) * 3 + 1]
                    + ov[c * 3 + 2] * w_s1[(2 * 3 + c) * 3 + 2];
            }
            v0 = fmaxf(v0, 0.f); v1 = fmaxf(v1, 0.f); v2 = fmaxf(v2, 0.f);
            #pragma unroll
            for (int o = 0; o < 20; ++o) {
                acc[o] += v0 * w_s2[(o * 3 + 0) * 48 + t]
                        + v1 * w_s2[(o * 3 + 1) * 48 + t]
                        + v2 * w_s2[(o * 3 + 2) * 48 + t];
            }
        }

        // ---------------- long path third ----------------
        const int rb0 = (0 * 64 + lane) * 51;
        const int rb1 = (1 * 64 + lane) * 51;
        const int rb2 = (2 * 64 + lane) * 51;
        const int l0 = (w == 0) ? 0 : (w == 1) ? 17 : 34;
        const int l1 = (w == 0) ? 17 : (w == 1) ? 34 : 50;
        #pragma unroll 1
        for (int t = l0; t < l1; ++t) {
            mx0 = fmaxf(mx0, lds[rb0 + t]);
            mx1 = fmaxf(mx1, lds[rb1 + t]);
            mx2 = fmaxf(mx2, lds[rb2 + t]);
        }
    } else {
        // ---------------- mid path: t in [(w-3)*6, (w-3)*6+6) --------------
        #pragma unroll
        for (int o = 0; o < 20; ++o) acc[o] = (w == 3) ? b_m2[o] : 0.f;

        const float m10 = b_m1[0], m11 = b_m1[1], m12 = b_m1[2];
        const int t0 = (w - 3) * 6;

        #pragma unroll 1
        for (int t = t0; t < t0 + 6; ++t) {
            float v0 = m10, v1 = m11, v2 = m12;
            #pragma unroll
            for (int c = 0; c < 3; ++c) {
                const int base = (c * 64 + lane) * 51 + t;
                float p0 = 0.f, p1 = 0.f, p2 = 0.f;   // per-channel chains
                #pragma unroll
                for (int d = 0; d < 21; ++d) {
                    const float ov = lds[base + d];
                    p0 += ov * w_m1[(0 * 3 + c) * 21 + d];
                    p1 += ov * w_m1[(1 * 3 + c) * 21 + d];
                    p2 += ov * w_m1[(2 * 3 + c) * 21 + d];
                }
                v0 += p0; v1 += p1; v2 += p2;
            }
            v0 = fmaxf(v0, 0.f); v1 = fmaxf(v1, 0.f); v2 = fmaxf(v2, 0.f);
            #pragma unroll
            for (int o = 0; o < 20; ++o) {
                acc[o] += v0 * w_m2[(o * 3 + 0) * 30 + t]
                        + v1 * w_m2[(o * 3 + 1) * 30 + t]
                        + v2 * w_m2[(o * 3 + 2) * 30 + t];
            }
        }
    }

    // ---- exchange partials via the (now dead) obs tile ----
    __syncthreads();
    if (w == 1 || w == 2) {
        float* r = lds + (w - 1) * 1472 + lane;
        #pragma unroll
        for (int o = 0; o < 20; ++o) r[o * 64] = acc[o];
        r[20 * 64] = mx0;
        r[21 * 64] = mx1;
        r[22 * 64] = mx2;
    } else if (w >= 4) {
        float* r = lds + 2944 + (w - 4) * 1280 + lane;
        #pragma unroll
        for (int o = 0; o < 20; ++o) r[o * 64] = acc[o];
    }
    __syncthreads();

    if (lane < nrows) {
        float* xp = x + ((size_t)b * Nn + tile0 + lane) * FSn;
        if (w == 0) {
            #pragma unroll
            for (int o = 0; o < 20; ++o) {
                const int a = o * 64 + lane;
                xp[o] = fmaxf(acc[o] + lds[a] + lds[1472 + a], 0.f);
            }
            {
                const int a0 = 20 * 64 + lane, a1 = 21 * 64 + lane, a2 = 22 * 64 + lane;
                xp[40] = fmaxf(fmaxf(mx0, fmaxf(lds[a0], lds[1472 + a0])), 0.f);
                xp[41] = fmaxf(fmaxf(mx1, fmaxf(lds[a1], lds[1472 + a1])), 0.f);
                xp[42] = fmaxf(fmaxf(mx2, fmaxf(lds[a2], lds[1472 + a2])), 0.f);
            }
        } else if (w == 3) {
            #pragma unroll
            for (int o = 0; o < 20; ++o) {
                const int a = 2944 + o * 64 + lane;
                xp[20 + o] = fmaxf(acc[o] + lds[a] + lds[a + 1280]
                                          + lds[a + 2560] + lds[a + 3840], 0.f);
            }
        }
    }
}

// ---------------------------------------------------------------------------
// Transpose + fp16 convert: x[b][nf] (f32) -> xT[nf][b] (f16)
// ---------------------------------------------------------------------------
__global__ __launch_bounds__(256) void k_transpose(const float* __restrict__ x,
                                                   __half* __restrict__ xT)
{
    __shared__ float tile[64][129];
    const int c0  = blockIdx.x * 64;
    const int tid = threadIdx.x;

    const int j  = tid & 63;
    const int bs = tid >> 6;
    for (int bb = bs; bb < Bn; bb += 4) {
        int c = c0 + j;
        if (c < NFtot) tile[j][bb] = x[(size_t)bb * NFtot + c];
    }
    __syncthreads();

    const int b  = tid & 127;
    for (int jj = (tid >> 7); jj < 64; jj += 2) {
        int c = c0 + jj;
        if (c < NFtot) xT[(size_t)c * Bn + b] = __float2half(tile[jj][b]);
    }
}

// ---------------------------------------------------------------------------
// CSR build
// ---------------------------------------------------------------------------
__global__ void k_zero(int* __restrict__ cnt, int* __restrict__ pos)
{
    int i = blockIdx.x * blockDim.x + threadIdx.x;
    if (i < 4096) { cnt[i] = 0; pos[i] = 0; }
}

__global__ void k_count(const int* __restrict__ ei, const int* __restrict__ et,
                        int* __restrict__ cnt)
{
    int e = blockIdx.x * blockDim.x + threadIdx.x;
    if (e < En) {
        int dst = ei[En + e];
        atomicAdd(&cnt[dst * Rn + et[e]], 1);
    }
}

__global__ __launch_bounds__(1024) void k_scan(const int* __restrict__ cnt,
                                               int* __restrict__ off)
{
    __shared__ int sums[1024];
    int tid = threadIdx.x;
    int base = tid * 4;
    int c[4];
    int ts = 0;
    #pragma unroll
    for (int k = 0; k < 4; ++k) {
        int i = base + k;
        c[k] = (i < Nn * Rn) ? cnt[i] : 0;
        ts += c[k];
    }
    sums[tid] = ts;
    __syncthreads();
    for (int d = 1; d < 1024; d <<= 1) {
        int t = 0;
        if (tid >= d) t = sums[tid - d];
        __syncthreads();
        sums[tid] += t;
        __syncthreads();
    }
    int excl = sums[tid] - ts;
    #pragma unroll
    for (int k = 0; k < 4; ++k) {
        int i = base + k;
        off[i] = excl;
        excl += c[k];
    }
}

__global__ void k_fill(const int* __restrict__ ei, const int* __restrict__ et,
                       const int* __restrict__ off, int* __restrict__ pos,
                       int* __restrict__ csr)
{
    int e = blockIdx.x * blockDim.x + threadIdx.x;
    if (e < En) {
        int src = ei[e];
        int dst = ei[En + e];
        int seg = dst * Rn + et[e];
        int p = atomicAdd(&pos[seg], 1);
        csr[off[seg] + p] = src;
    }
}

// ---------------------------------------------------------------------------
// Kernel 2 (fused): per-selected-dst gather (all 4 relations in parallel) +
// relational transform + root + leaky + final projection.
// grid = 500; 512 thr.
//   gather phase: r = tid>>7, fc = (tid>>5)&3, b4 = tid&31.
//     f = fc + 4k (k < nk; nk = 11,11,11,10), float2 = 4 halves over b.
//     means written to LDS ab[4][43][128] fp16 (44 KB).
//   transform phase: fs = tid>>7, b = tid&127 — k_trans's body, a[] from LDS.
// LDS: ab 44 KB + srcs 2 KB + cnts; red[44][128] f32 aliases ab after sync.
// ---------------------------------------------------------------------------
__global__ __launch_bounds__(512) void k_graph(
    const __half* __restrict__ xT,
    const float* __restrict__ w_rel, const float* __restrict__ w_root,
    const float* __restrict__ b_g,
    const float* __restrict__ w_fin, const float* __restrict__ b_fin,
    const float* __restrict__ la,
    const int* __restrict__ csr, const int* __restrict__ off,
    const int* __restrict__ cnt, const int* __restrict__ sel,
    float* __restrict__ logitT)
{
    __shared__ __align__(16) char smem[44032 + 2048 + 32];
    __half* ab    = (__half*)smem;                 // [4][43][128] halves
    int*    srcs  = (int*)(smem + 44032);          // [4][128]
    int*    scnt  = (int*)(smem + 44032 + 2048);   // [4] clamped
    int*    tcnt  = scnt + 4;                      // [4] true
    float*  red   = (float*)smem;                  // [44][128] aliases ab

    const int i   = blockIdx.x;
    const int dst = sel[i];
    const int tid = threadIdx.x;

    // ---- phase 0: stage edge lists ----
    {
        const int r = tid >> 7;
        const int j = tid & 127;
        const int c = cnt[dst * Rn + r];
        const int o = off[dst * Rn + r];
        if (j == 0) { tcnt[r] = c; scnt[r] = (c < 128) ? c : 128; }
        if (j < c && j < 128) srcs[r * 128 + j] = csr[o + j];
    }
    __syncthreads();

    // ---- phase 1: gather means, all 4 relations in parallel ----
    {
        const int r  = tid >> 7;          // 0..3
        const int fc = (tid >> 5) & 3;    // 0..3
        const int b4 = tid & 31;          // float2 group over b
        const int nk = (fc < 3) ? 11 : 10;    // f = fc + 4k < 43

        float4 acc[11];
        #pragma unroll
        for (int k = 0; k < 11; ++k) acc[k] = make_float4(0.f, 0.f, 0.f, 0.f);

        const int cc = scnt[r];
        const float2* xT2 = (const float2*)xT;   // 1 float2 = 4 halves
        for (int j = 0; j < cc; ++j) {
            const int src = srcs[r * 128 + j];
            const float2* base = xT2 + (size_t)src * (FSn * 32) + (size_t)fc * 32 + b4;
            #pragma unroll
            for (int k = 0; k < 11; ++k) {
                if (k < nk) {
                    float2 raw = base[(size_t)k * 4 * 32];
                    const __half2 h0 = ((const __half2*)&raw)[0];
                    const __half2 h1 = ((const __half2*)&raw)[1];
                    const float2 f0 = __half22float2(h0);
                    const float2 f1 = __half22float2(h1);
                    acc[k].x += f0.x; acc[k].y += f0.y;
                    acc[k].z += f1.x; acc[k].w += f1.y;
                }
            }
        }

        const int  tc  = tcnt[r];
        const float inv = (tc > 0) ? 1.f / (float)tc : 0.f;
        float2* ab2 = (float2*)ab;
        #pragma unroll
        for (int k = 0; k < 11; ++k) {
            if (k < nk) {
                const int f = fc + 4 * k;
                float2 st;
                ((__half2*)&st)[0] = __floats2half2_rn(acc[k].x * inv, acc[k].y * inv);
                ((__half2*)&st)[1] = __floats2half2_rn(acc[k].z * inv, acc[k].w * inv);
                ab2[(r * FSn + f) * 32 + b4] = st;
            }
        }
    }
    __syncthreads();

    // ---- phase 2: transform (k_trans body; a[] from LDS) ----
    const int fs = tid >> 7;
    const int b  = tid & 127;
    const int f0 = fs * 11;
    const int nf = (fs == 3) ? 10 : 11;

    float a[5][11];
    #pragma unroll
    for (int rr = 0; rr < 4; ++rr) {
        #pragma unroll
        for (int k = 0; k < 11; ++k)
            a[rr][k] = (k < nf) ? __half2float(ab[(rr * FSn + f0 + k) * Bn + b]) : 0.f;
    }
    {
        const __half* xp = xT + ((size_t)dst * FSn + f0) * Bn + b;
        #pragma unroll
        for (int k = 0; k < 11; ++k)
            a[4][k] = (k < nf) ? __half2float(xp[(size_t)k * Bn]) : 0.f;
    }

    float accg[FSn];
    #pragma unroll
    for (int g = 0; g < FSn; ++g) accg[g] = 0.f;
    float psum = 0.f;

    #pragma unroll
    for (int k = 0; k < 11; ++k) {
        if (k < nf) {
            const int f = f0 + k;
            #pragma unroll
            for (int rr = 0; rr < 5; ++rr) {
                const float av = a[rr][k];
                const float* wrow = (rr < 4)
                    ? (w_rel + ((size_t)rr * FSn + f) * FSn)
                    : (w_root + (size_t)f * FSn);
                #pragma unroll
                for (int g = 0; g < FSn; ++g) accg[g] += av * wrow[g];
            }
            psum += a[4][k] * w_fin[1 + f];
        }
    }

    __syncthreads();   // ab dead; red (aliasing ab) now safe to write

    if (fs == 3) {
        #pragma unroll
        for (int g = 0; g < FSn; ++g) red[g * Bn + b] = accg[g];
        red[FSn * Bn + b] = psum;
    }
    __syncthreads();
    if (fs == 2) {
        #pragma unroll
        for (int g = 0; g < FSn; ++g) red[g * Bn + b] += accg[g];
        red[FSn * Bn + b] += psum;
    }
    __syncthreads();
    if (fs == 1) {
        #pragma unroll
        for (int g = 0; g < FSn; ++g) red[g * Bn + b] += accg[g];
        red[FSn * Bn + b] += psum;
    }
    __syncthreads();
    if (fs == 0) {
        float logit = b_fin[0] + w_fin[0] * la[(size_t)b * (NSELn + 1) + 1 + i]
                    + psum + red[FSn * Bn + b];
        #pragma unroll
        for (int g = 0; g < FSn; ++g) {
            float v = accg[g] + red[g * Bn + b] + b_g[g];
            v = (v > 0.f) ? v : 0.01f * v;
            logit += v * w_fin[44 + g];
        }
        logitT[(size_t)i * Bn + b] = logit;
    }
}

// ---------------------------------------------------------------------------
// Kernel 3: softmax over [0, logits(500)] per batch. Block per b.
// ---------------------------------------------------------------------------
__global__ __launch_bounds__(512) void k_softmax(const float* __restrict__ logitT,
                                                 float* __restrict__ out)
{
    __shared__ float red[512];
    const int b   = blockIdx.x;
    const int tid = threadIdx.x;

    const float l = (tid < NSELn) ? logitT[(size_t)tid * Bn + b] : -1e30f;
    red[tid] = l;
    __syncthreads();
    for (int s = 256; s > 0; s >>= 1) {
        if (tid < s) red[tid] = fmaxf(red[tid], red[tid + s]);
        __syncthreads();
    }
    const float m = fmaxf(red[0], 0.f);
    __syncthreads();

    const float e = (tid < NSELn) ? expf(l - m) : 0.f;
    red[tid] = e;
    __syncthreads();
    for (int s = 256; s > 0; s >>= 1) {
        if (tid < s) red[tid] += red[tid + s];
        __syncthreads();
    }
    const float e0  = expf(-m);
    const float inv = 1.f / (red[0] + e0);

    if (tid == 0) out[(size_t)b * (NSELn + 1)] = e0 * inv;
    if (tid < NSELn) out[(size_t)b * (NSELn + 1) + 1 + tid] = e * inv;
}

// ---------------------------------------------------------------------------
extern "C" void kernel_launch(void* const* d_in, const int* in_sizes, int n_in,
                              void* d_out, int out_size, void* d_ws, size_t ws_size,
                              hipStream_t stream)
{
    const float* obs    = (const float*)d_in[0];
    const float* la     = (const float*)d_in[1];
    const float* w_s1   = (const float*)d_in[2];
    const float* b_s1   = (const float*)d_in[3];
    const float* w_s2   = (const float*)d_in[4];
    const float* b_s2   = (const float*)d_in[5];
    const float* w_m1   = (const float*)d_in[6];
    const float* b_m1   = (const float*)d_in[7];
    const float* w_m2   = (const float*)d_in[8];
    const float* b_m2   = (const float*)d_in[9];
    const float* w_rel  = (const float*)d_in[10];
    const float* w_root = (const float*)d_in[11];
    const float* b_g    = (const float*)d_in[12];
    const float* w_fin  = (const float*)d_in[13];
    const float* b_fin  = (const float*)d_in[14];
    const int*   ei     = (const int*)d_in[15];
    const int*   et     = (const int*)d_in[16];
    const int*   sel    = (const int*)d_in[17];
    float*       out    = (float*)d_out;

    // workspace (bytes):
    //   x   : f32, 22,016,000 B at 0
    //   xTh : half, 11,008,000 B at 22,016,000
    //   cnt/off/pos (4096 ints each), csr (32000 ints), logitT (500*128 f32)
    char* wsb     = (char*)d_ws;
    float* x      = (float*)wsb;
    __half* xTh   = (__half*)(wsb + 22016000);
    int*   cnt    = (int*)(wsb + 33024000);
    int*   offb   = cnt + 4096;
    int*   pos    = offb + 4096;
    int*   csr    = pos + 4096;
    float* logitT = (float*)(csr + 32000);

    hipLaunchKernelGGL(k_zero,  dim3(16),  dim3(256), 0, stream, cnt, pos);
    hipLaunchKernelGGL(k_count, dim3((En + 255) / 256), dim3(256), 0, stream, ei, et, cnt);
    hipLaunchKernelGGL(k_scan,  dim3(1),   dim3(1024), 0, stream, cnt, offb);
    hipLaunchKernelGGL(k_fill,  dim3((En + 255) / 256), dim3(256), 0, stream, ei, et, offb, pos, csr);

    hipLaunchKernelGGL(k_temporal, dim3(Bn, (Nn + 63) / 64), dim3(512), 0, stream,
                       obs, w_s1, b_s1, w_s2, b_s2, w_m1, b_m1, w_m2, b_m2, x);

    hipLaunchKernelGGL(k_transpose, dim3((NFtot + 63) / 64), dim3(256), 0, stream, x, xTh);

    hipLaunchKernelGGL(k_graph, dim3(NSELn), dim3(512), 0, stream,
                       xTh, w_rel, w_root, b_g, w_fin, b_fin, la,
                       csr, offb, cnt, sel, logitT);

    hipLaunchKernelGGL(k_softmax, dim3(Bn), dim3(512), 0, stream, logitT, out);
}